// Round 1
// baseline (324.348 us; speedup 1.0000x reference)
//
#include <hip/hip_runtime.h>
#include <hip/hip_bf16.h>
#include <stdint.h>

// Problem dims (fixed)
#define BATCH   2
#define SEQ     2048
#define D_MODEL 1024
#define NHEADS  16
#define HEADDIM 64
#define M_ROWS  (BATCH * SEQ)   // 4096

typedef __attribute__((ext_vector_type(8))) short bf16x8;   // 8 bf16 in 4 VGPRs
typedef __attribute__((ext_vector_type(4))) float f32x4;

typedef __attribute__((address_space(3))) void       lds_void;
typedef const __attribute__((address_space(1))) void glb_void;

#define GLD_LDS16(g, l) \
  __builtin_amdgcn_global_load_lds((glb_void*)(g), (lds_void*)(l), 16, 0, 0)

__device__ __forceinline__ unsigned short f2bf(float f) {
  union { float f; unsigned u; } v; v.f = f;
  unsigned r = v.u + 0x7fff + ((v.u >> 16) & 1);   // round-to-nearest-even
  return (unsigned short)(r >> 16);
}

// ---------------------------------------------------------------- converts
__global__ void cvt_bf16(const float* __restrict__ x, unsigned short* __restrict__ y, int n) {
  int i = (blockIdx.x * blockDim.x + threadIdx.x) * 4;
  if (i + 3 < n) {
    float4 v = *(const float4*)(x + i);
    ushort4 o; o.x = f2bf(v.x); o.y = f2bf(v.y); o.z = f2bf(v.z); o.w = f2bf(v.w);
    *(ushort4*)(y + i) = o;
  }
}

// W [K=1024][N=1024] fp32 -> WT [N][K] bf16
__global__ void wtrans(const float* __restrict__ W, unsigned short* __restrict__ WT) {
  __shared__ float t[32][33];
  int bx = blockIdx.x * 32, by = blockIdx.y * 32;
  int tx = threadIdx.x, ty = threadIdx.y;
  t[ty][tx] = W[(size_t)(by + ty) * D_MODEL + bx + tx];
  __syncthreads();
  WT[(size_t)(bx + ty) * D_MODEL + by + tx] = f2bf(t[tx][ty]);
}

// ---------------------------------------------------------------- GEMM
// C[M,N] = A[M,K] @ B[K,N] + bias, with B given transposed (BT[N][K]).
// 128x128 tile, BK=32, 4 waves (2x2), each wave 64x64 out (4x4 frags 16x16x32).
// mode 0/1: dst bf16 [B,H,L,HD]   (Q / K heads layout)
// mode 2  : dst bf16 [B,H,HD,L]   (V transposed)
// mode 3  : dst fp32 [M,N] row-major (final output)
struct GemmArgs {
  const unsigned short* A[3];
  const unsigned short* B[3];
  const float*          bias[3];
  void*                 dst[3];
  int                   mode0;
};

__global__ void gemm_bf16(GemmArgs ga) {
  const int z = blockIdx.z;
  const unsigned short* __restrict__ A  = ga.A[z];
  const unsigned short* __restrict__ BT = ga.B[z];
  const float* __restrict__ bias        = ga.bias[z];
  void* dst = ga.dst[z];
  const int mode = ga.mode0 + z;

  const int K = D_MODEL;
  const int bn0 = blockIdx.x * 128, bm0 = blockIdx.y * 128;
  __shared__ unsigned short lds_a[128 * 32];
  __shared__ unsigned short lds_b[128 * 32];
  const int tid = threadIdx.x, wave = tid >> 6, lane = tid & 63;
  const int wr = wave >> 1, wc = wave & 1;
  const int lr = lane & 15, lq = lane >> 4;
  const int srow = lane >> 2, scol = (lane & 3) * 8;   // staging: 16B per lane

  f32x4 acc[4][4] = {};

  for (int k0 = 0; k0 < K; k0 += 32) {
    __syncthreads();   // prev tile's ds_reads done before overwrite
#pragma unroll
    for (int c = 0; c < 2; ++c) {
      int ch  = c * 4 + wave;            // 8 chunks of 16 rows
      int row = ch * 16 + srow;
      GLD_LDS16(A  + (size_t)(bm0 + row) * K + k0 + scol, lds_a + ch * 512);
      GLD_LDS16(BT + (size_t)(bn0 + row) * K + k0 + scol, lds_b + ch * 512);
    }
    __syncthreads();   // drains vmcnt: LDS tiles ready

    bf16x8 af[4], bfr[4];
#pragma unroll
    for (int i = 0; i < 4; ++i) {
      af[i]  = *(const bf16x8*)(lds_a + (wr * 64 + i * 16 + lr) * 32 + lq * 8);
      bfr[i] = *(const bf16x8*)(lds_b + (wc * 64 + i * 16 + lr) * 32 + lq * 8);
    }
#pragma unroll
    for (int mi = 0; mi < 4; ++mi)
#pragma unroll
      for (int ni = 0; ni < 4; ++ni)
        acc[mi][ni] = __builtin_amdgcn_mfma_f32_16x16x32_bf16(af[mi], bfr[ni], acc[mi][ni], 0, 0, 0);
  }

  // epilogue: D mapping col = lane&15, row = (lane>>4)*4 + reg
#pragma unroll
  for (int mi = 0; mi < 4; ++mi) {
#pragma unroll
    for (int ni = 0; ni < 4; ++ni) {
      const int n  = bn0 + wc * 64 + ni * 16 + lr;
      const float bv = bias[n];
      const int mb = bm0 + wr * 64 + mi * 16 + lq * 4;
      f32x4 v = acc[mi][ni];
      if (mode == 3) {
        float* o = (float*)dst;
#pragma unroll
        for (int r = 0; r < 4; ++r) o[(size_t)(mb + r) * D_MODEL + n] = v[r] + bv;
      } else if (mode == 2) {
        // V^T: [B,H,HD,L]; 4 consecutive rows (l) pack to one 8B store
        const int b = mb >> 11, l = mb & 2047;
        const int h = n >> 6, hd = n & 63;
        ushort4 pk;
        pk.x = f2bf(v[0] + bv); pk.y = f2bf(v[1] + bv);
        pk.z = f2bf(v[2] + bv); pk.w = f2bf(v[3] + bv);
        *(ushort4*)((unsigned short*)dst + ((size_t)((b * NHEADS + h) * HEADDIM + hd)) * SEQ + l) = pk;
      } else {
        unsigned short* o = (unsigned short*)dst;
        const int h = n >> 6, hd = n & 63;
#pragma unroll
        for (int r = 0; r < 4; ++r) {
          int m = mb + r; int b = m >> 11, l = m & 2047;
          o[((size_t)(b * NHEADS + h) * SEQ + l) * HEADDIM + hd] = f2bf(v[r] + bv);
        }
      }
    }
  }
}

// ---------------------------------------------------------------- flash attention
// grid: (L/64, B*H). 4 waves/block, each wave owns 16 q-rows. 64-key tiles.
// K and V^T fragments read directly from global (per-head K+V = 512KB, L2-resident).
__global__ void flash_attn(const unsigned short* __restrict__ Q,
                           const unsigned short* __restrict__ Kb,
                           const unsigned short* __restrict__ VT,
                           unsigned short* __restrict__ O) {
  const int head = blockIdx.y;                 // b*16 + h
  const int b = head >> 4, h = head & 15;
  const int wave = threadIdx.x >> 6, lane = threadIdx.x & 63;
  const int lr = lane & 15, lq = lane >> 4;
  const int q0 = blockIdx.x * 64 + wave * 16;

  const unsigned short* Qh = Q  + (size_t)head * SEQ * HEADDIM;
  const unsigned short* Kh = Kb + (size_t)head * SEQ * HEADDIM;
  const unsigned short* Vh = VT + (size_t)head * HEADDIM * SEQ;

  __shared__ unsigned short p_lds[4][16 * 64];   // wave-private P transpose buffer
  unsigned short* pw = p_lds[wave];

  bf16x8 qf[2];
#pragma unroll
  for (int ks = 0; ks < 2; ++ks)
    qf[ks] = *(const bf16x8*)(Qh + (size_t)(q0 + lr) * HEADDIM + ks * 32 + lq * 8);

  f32x4 oacc[4] = {};
  float mrun[4], lrun[4];
#pragma unroll
  for (int r = 0; r < 4; ++r) { mrun[r] = -1e30f; lrun[r] = 0.f; }

  for (int k0 = 0; k0 < SEQ; k0 += 64) {
    // S = Q K^T  (rows q=lq*4+r, cols key=n*16+lr)
    f32x4 s[4] = {};
#pragma unroll
    for (int n = 0; n < 4; ++n)
#pragma unroll
      for (int ks = 0; ks < 2; ++ks) {
        bf16x8 kf = *(const bf16x8*)(Kh + (size_t)(k0 + n * 16 + lr) * HEADDIM + ks * 32 + lq * 8);
        s[n] = __builtin_amdgcn_mfma_f32_16x16x32_bf16(qf[ks], kf, s[n], 0, 0, 0);
      }
#pragma unroll
    for (int n = 0; n < 4; ++n) s[n] *= 0.125f;   // 1/sqrt(64)

    // row max across 16 lanes
    float mx[4];
#pragma unroll
    for (int r = 0; r < 4; ++r)
      mx[r] = fmaxf(fmaxf(s[0][r], s[1][r]), fmaxf(s[2][r], s[3][r]));
#pragma unroll
    for (int d = 1; d < 16; d <<= 1)
#pragma unroll
      for (int r = 0; r < 4; ++r) mx[r] = fmaxf(mx[r], __shfl_xor(mx[r], d));

    float al[4], rs[4];
#pragma unroll
    for (int r = 0; r < 4; ++r) {
      float mn = fmaxf(mrun[r], mx[r]);
      al[r] = __expf(mrun[r] - mn);
      mrun[r] = mn; rs[r] = 0.f;
    }
#pragma unroll
    for (int n = 0; n < 4; ++n)
#pragma unroll
      for (int r = 0; r < 4; ++r) {
        float p = __expf(s[n][r] - mrun[r]);
        s[n][r] = p; rs[r] += p;
      }
#pragma unroll
    for (int d = 1; d < 16; d <<= 1)
#pragma unroll
      for (int r = 0; r < 4; ++r) rs[r] += __shfl_xor(rs[r], d);
#pragma unroll
    for (int r = 0; r < 4; ++r) lrun[r] = lrun[r] * al[r] + rs[r];
#pragma unroll
    for (int n = 0; n < 4; ++n) {
      oacc[n][0] *= al[0]; oacc[n][1] *= al[1];
      oacc[n][2] *= al[2]; oacc[n][3] *= al[3];
    }

    // P -> A-fragment layout via wave-private LDS (same-wave DS is in-order)
#pragma unroll
    for (int n = 0; n < 4; ++n)
#pragma unroll
      for (int r = 0; r < 4; ++r)
        pw[(lq * 4 + r) * 64 + n * 16 + lr] = f2bf(s[n][r]);
    bf16x8 pf[2];
#pragma unroll
    for (int ks = 0; ks < 2; ++ks)
      pf[ks] = *(const bf16x8*)(pw + lr * 64 + ks * 32 + lq * 8);

    // O += P @ V   (B^T = VT[d][key], contiguous along keys)
#pragma unroll
    for (int n = 0; n < 4; ++n)
#pragma unroll
      for (int ks = 0; ks < 2; ++ks) {
        bf16x8 vf = *(const bf16x8*)(Vh + (size_t)(n * 16 + lr) * SEQ + k0 + ks * 32 + lq * 8);
        oacc[n] = __builtin_amdgcn_mfma_f32_16x16x32_bf16(pf[ks], vf, oacc[n], 0, 0, 0);
      }
  }

  float inv[4];
#pragma unroll
  for (int r = 0; r < 4; ++r) inv[r] = 1.f / lrun[r];
#pragma unroll
  for (int n = 0; n < 4; ++n)
#pragma unroll
    for (int r = 0; r < 4; ++r) {
      int qi = q0 + lq * 4 + r;
      O[((size_t)(b * SEQ + qi) * NHEADS + h) * HEADDIM + n * 16 + lr] = f2bf(oacc[n][r] * inv[r]);
    }
}

// ---------------------------------------------------------------- launch
extern "C" void kernel_launch(void* const* d_in, const int* in_sizes, int n_in,
                              void* d_out, int out_size, void* d_ws, size_t ws_size,
                              hipStream_t stream) {
  const float* query = (const float*)d_in[0];
  const float* key_  = (const float*)d_in[1];
  const float* value = (const float*)d_in[2];
  const float* Wq = (const float*)d_in[3];
  const float* bq = (const float*)d_in[4];
  const float* Wk = (const float*)d_in[5];
  const float* bk = (const float*)d_in[6];
  const float* Wv = (const float*)d_in[7];
  const float* bv = (const float*)d_in[8];
  const float* Wo = (const float*)d_in[9];
  const float* bo = (const float*)d_in[10];

  const size_t NX = (size_t)M_ROWS * D_MODEL;       // 4M activations
  const size_t NW = (size_t)D_MODEL * D_MODEL;      // 1M weights

  char* ws = (char*)d_ws;
  size_t off = 0;
  auto alloc = [&](size_t bytes) { char* p = ws + off; off += (bytes + 255) & ~255ULL; return p; };
  unsigned short* Xq   = (unsigned short*)alloc(NX * 2);
  unsigned short* Xk   = (unsigned short*)alloc(NX * 2);
  unsigned short* Xv   = (unsigned short*)alloc(NX * 2);
  unsigned short* WqT  = (unsigned short*)alloc(NW * 2);
  unsigned short* WkT  = (unsigned short*)alloc(NW * 2);
  unsigned short* WvT  = (unsigned short*)alloc(NW * 2);
  unsigned short* WoT  = (unsigned short*)alloc(NW * 2);
  unsigned short* Qh   = (unsigned short*)alloc(NX * 2);
  unsigned short* Kh   = (unsigned short*)alloc(NX * 2);
  unsigned short* VTh  = (unsigned short*)alloc(NX * 2);
  unsigned short* Obuf = (unsigned short*)alloc(NX * 2);

  cvt_bf16<<<(int)(NX / 4 / 256), 256, 0, stream>>>(query, Xq, (int)NX);
  cvt_bf16<<<(int)(NX / 4 / 256), 256, 0, stream>>>(key_,  Xk, (int)NX);
  cvt_bf16<<<(int)(NX / 4 / 256), 256, 0, stream>>>(value, Xv, (int)NX);

  dim3 tb(32, 32);
  wtrans<<<dim3(32, 32), tb, 0, stream>>>(Wq, WqT);
  wtrans<<<dim3(32, 32), tb, 0, stream>>>(Wk, WkT);
  wtrans<<<dim3(32, 32), tb, 0, stream>>>(Wv, WvT);
  wtrans<<<dim3(32, 32), tb, 0, stream>>>(Wo, WoT);

  GemmArgs pa;
  pa.A[0] = Xq;  pa.A[1] = Xk;  pa.A[2] = Xv;
  pa.B[0] = WqT; pa.B[1] = WkT; pa.B[2] = WvT;
  pa.bias[0] = bq; pa.bias[1] = bk; pa.bias[2] = bv;
  pa.dst[0] = Qh; pa.dst[1] = Kh; pa.dst[2] = VTh;
  pa.mode0 = 0;
  gemm_bf16<<<dim3(D_MODEL / 128, M_ROWS / 128, 3), 256, 0, stream>>>(pa);

  flash_attn<<<dim3(SEQ / 64, BATCH * NHEADS), 256, 0, stream>>>(Qh, Kh, VTh, Obuf);

  GemmArgs fa = {};
  fa.A[0] = Obuf; fa.B[0] = WoT; fa.bias[0] = bo; fa.dst[0] = d_out; fa.mode0 = 3;
  gemm_bf16<<<dim3(D_MODEL / 128, M_ROWS / 128, 1), 256, 0, stream>>>(fa);
}

// Round 3
// 174.832 us; speedup vs baseline: 1.8552x; 1.8552x over previous
//
#include <hip/hip_runtime.h>
#include <hip/hip_bf16.h>
#include <stdint.h>

// Problem dims (fixed)
#define BATCH   2
#define SEQ     2048
#define D_MODEL 1024
#define NHEADS  16
#define HEADDIM 64
#define M_ROWS  (BATCH * SEQ)   // 4096

typedef __attribute__((ext_vector_type(8))) short bf16x8;   // 8 bf16 in 4 VGPRs
typedef __attribute__((ext_vector_type(4))) float f32x4;

typedef __attribute__((address_space(3))) void       lds_void;
typedef const __attribute__((address_space(1))) void glb_void;

#define GLD_LDS16(g, l) \
  __builtin_amdgcn_global_load_lds((glb_void*)(g), (lds_void*)(l), 16, 0, 0)

__device__ __forceinline__ unsigned short f2bf(float f) {
  union { float f; unsigned u; } v; v.f = f;
  unsigned r = v.u + 0x7fff + ((v.u >> 16) & 1);   // round-to-nearest-even
  return (unsigned short)(r >> 16);
}

__device__ __forceinline__ unsigned pkbf(float a, float b) {
  __hip_bfloat162 h = __float22bfloat162_rn(float2{a, b});
  union { __hip_bfloat162 h; unsigned u; } cv; cv.h = h; return cv.u;  // a -> low 16
}

// ---------------------------------------------------------------- converts
struct Cvt3Args { const float* x[3]; unsigned short* y[3]; };
__global__ void cvt_bf16_3(Cvt3Args a, int n) {
  const float* x = a.x[blockIdx.z];
  unsigned short* y = a.y[blockIdx.z];
  int i = (blockIdx.x * blockDim.x + threadIdx.x) * 4;
  if (i + 3 < n) {
    float4 v = *(const float4*)(x + i);
    ushort4 o; o.x = f2bf(v.x); o.y = f2bf(v.y); o.z = f2bf(v.z); o.w = f2bf(v.w);
    *(ushort4*)(y + i) = o;
  }
}

// W [K=1024][N=1024] fp32 -> WT [N][K] bf16  (4 weights batched on z)
struct Wt4Args { const float* W[4]; unsigned short* WT[4]; };
__global__ void wtrans4(Wt4Args a) {
  const float* W = a.W[blockIdx.z];
  unsigned short* WT = a.WT[blockIdx.z];
  __shared__ float t[32][33];
  int bx = blockIdx.x * 32, by = blockIdx.y * 32;
  int tx = threadIdx.x, ty = threadIdx.y;
  t[ty][tx] = W[(size_t)(by + ty) * D_MODEL + bx + tx];
  __syncthreads();
  WT[(size_t)(bx + ty) * D_MODEL + by + tx] = f2bf(t[tx][ty]);
}

// ---------------------------------------------------------------- GEMM
// C[M,N] = A[M,K] @ B[K,N] + bias, with B given transposed (BT[N][K]).
// 128x128 tile, BK=32, 4 waves (2x2), each wave 64x64 out (4x4 frags 16x16x32).
// mode 0/1: dst bf16 [B,H,L,HD]   (Q / K heads layout)
// mode 2  : dst bf16 [B,H,HD,L]   (V transposed)
// mode 3  : dst fp32 [M,N] row-major (final output)
struct GemmArgs {
  const unsigned short* A[3];
  const unsigned short* B[3];
  const float*          bias[3];
  void*                 dst[3];
  int                   mode0;
};

__global__ void gemm_bf16(GemmArgs ga) {
  const int z = blockIdx.z;
  const unsigned short* __restrict__ A  = ga.A[z];
  const unsigned short* __restrict__ BT = ga.B[z];
  const float* __restrict__ bias        = ga.bias[z];
  void* dst = ga.dst[z];
  const int mode = ga.mode0 + z;

  const int K = D_MODEL;
  const int bn0 = blockIdx.x * 128, bm0 = blockIdx.y * 128;
  __shared__ unsigned short lds_a[128 * 32];
  __shared__ unsigned short lds_b[128 * 32];
  const int tid = threadIdx.x, wave = tid >> 6, lane = tid & 63;
  const int wr = wave >> 1, wc = wave & 1;
  const int lr = lane & 15, lq = lane >> 4;
  const int srow = lane >> 2, scol = (lane & 3) * 8;   // staging: 16B per lane

  f32x4 acc[4][4] = {};

  for (int k0 = 0; k0 < K; k0 += 32) {
    __syncthreads();   // prev tile's ds_reads done before overwrite
#pragma unroll
    for (int c = 0; c < 2; ++c) {
      int ch  = c * 4 + wave;            // 8 chunks of 16 rows
      int row = ch * 16 + srow;
      GLD_LDS16(A  + (size_t)(bm0 + row) * K + k0 + scol, lds_a + ch * 512);
      GLD_LDS16(BT + (size_t)(bn0 + row) * K + k0 + scol, lds_b + ch * 512);
    }
    __syncthreads();   // drains vmcnt: LDS tiles ready

    bf16x8 af[4], bfr[4];
#pragma unroll
    for (int i = 0; i < 4; ++i) {
      af[i]  = *(const bf16x8*)(lds_a + (wr * 64 + i * 16 + lr) * 32 + lq * 8);
      bfr[i] = *(const bf16x8*)(lds_b + (wc * 64 + i * 16 + lr) * 32 + lq * 8);
    }
#pragma unroll
    for (int mi = 0; mi < 4; ++mi)
#pragma unroll
      for (int ni = 0; ni < 4; ++ni)
        acc[mi][ni] = __builtin_amdgcn_mfma_f32_16x16x32_bf16(af[mi], bfr[ni], acc[mi][ni], 0, 0, 0);
  }

  // epilogue: D mapping col = lane&15, row = (lane>>4)*4 + reg
#pragma unroll
  for (int mi = 0; mi < 4; ++mi) {
#pragma unroll
    for (int ni = 0; ni < 4; ++ni) {
      const int n  = bn0 + wc * 64 + ni * 16 + lr;
      const float bv = bias[n];
      const int mb = bm0 + wr * 64 + mi * 16 + lq * 4;
      f32x4 v = acc[mi][ni];
      if (mode == 3) {
        float* o = (float*)dst;
#pragma unroll
        for (int r = 0; r < 4; ++r) o[(size_t)(mb + r) * D_MODEL + n] = v[r] + bv;
      } else if (mode == 2) {
        // V^T: [B,H,HD,L]; 4 consecutive rows (l) pack to one 8B store
        const int b = mb >> 11, l = mb & 2047;
        const int h = n >> 6, hd = n & 63;
        ushort4 pk;
        pk.x = f2bf(v[0] + bv); pk.y = f2bf(v[1] + bv);
        pk.z = f2bf(v[2] + bv); pk.w = f2bf(v[3] + bv);
        *(ushort4*)((unsigned short*)dst + ((size_t)((b * NHEADS + h) * HEADDIM + hd)) * SEQ + l) = pk;
      } else {
        unsigned short* o = (unsigned short*)dst;
        const int h = n >> 6, hd = n & 63;
#pragma unroll
        for (int r = 0; r < 4; ++r) {
          int m = mb + r; int b = m >> 11, l = m & 2047;
          o[((size_t)(b * NHEADS + h) * SEQ + l) * HEADDIM + hd] = f2bf(v[r] + bv);
        }
      }
    }
  }
}

// ---------------------------------------------------------------- flash attention v2
// grid 512 blocks (logical: 16 q-blocks x 32 heads), 4 waves/block, 32 q-rows/wave.
// K/V tiles (64 keys) staged in LDS via global_load_lds, double-buffered, XOR-swizzled.
// Swapped QK^T: S^T = mfma(K, Q) -> lane owns q-col, 4 consecutive keys per reg.
__global__ __launch_bounds__(256, 2) void flash_attn(
    const unsigned short* __restrict__ Q,
    const unsigned short* __restrict__ Kb,
    const unsigned short* __restrict__ VT,
    unsigned short* __restrict__ O) {
  // XCD-aware swizzle: XCD k hosts heads 4k..4k+3 (2MB K/V per XCD L2)
  const int L = blockIdx.y * gridDim.x + blockIdx.x;   // linear dispatch id
  const int xcd = L & 7, slot = L >> 3;
  const int head = xcd * 4 + (slot >> 4);
  const int qb   = slot & 15;
  const int b = head >> 4, h = head & 15;

  const int tid = threadIdx.x, wave = tid >> 6, lane = tid & 63;
  const int lr = lane & 15, lq = lane >> 4;
  const int q0 = qb * 128 + wave * 32;

  const unsigned short* Qh = Q  + (size_t)head * SEQ * HEADDIM;
  const unsigned short* Kh = Kb + (size_t)head * SEQ * HEADDIM;
  const unsigned short* Vh = VT + (size_t)head * HEADDIM * SEQ;

  __shared__ unsigned short ldsK[2][64 * 64];
  __shared__ unsigned short ldsV[2][64 * 64];
  __shared__ unsigned short p_lds[4][32 * 72];   // wave-private, stride 72 (16B-aligned rows)
  unsigned short* pw = p_lds[wave];

  // stage one 64-key tile (K rows + V^T rows) with inverse-swizzled source (rule #21)
  const int r8 = lane >> 3;              // row&7 of the row this lane stages
  const int sc = (lane & 7) ^ r8;        // source chunk (involution)
#define STAGE_KV(buf, k0_)                                                          \
  {                                                                                 \
    _Pragma("unroll")                                                               \
    for (int it = 0; it < 2; ++it) {                                                \
      int row = it * 32 + wave * 8 + r8;                                            \
      GLD_LDS16(Kh + (size_t)(k0_ + row) * HEADDIM + sc * 8,                        \
                &ldsK[buf][(it * 256 + wave * 64) * 8]);                            \
      GLD_LDS16(Vh + (size_t)row * SEQ + (k0_) + sc * 8,                            \
                &ldsV[buf][(it * 256 + wave * 64) * 8]);                            \
    }                                                                               \
  }

  // Q fragments (B-operand: lane provides column q = qt*16+lr)
  bf16x8 qf[2][2];
#pragma unroll
  for (int qt = 0; qt < 2; ++qt)
#pragma unroll
    for (int ks = 0; ks < 2; ++ks)
      qf[qt][ks] = *(const bf16x8*)(Qh + (size_t)(q0 + qt * 16 + lr) * HEADDIM + ks * 32 + lq * 8);

  f32x4 oacc[2][4] = {};
  float mrun[2] = {-1e30f, -1e30f}, lpart[2] = {0.f, 0.f};
  const float C = 0.18033688011112f;     // 0.125 * log2(e)

  STAGE_KV(0, 0);
  __syncthreads();
  int cur = 0;

  for (int t = 0; t < SEQ / 64; ++t) {
    if (t + 1 < SEQ / 64) STAGE_KV(cur ^ 1, (t + 1) * 64);

    const unsigned short* lk = ldsK[cur];
    const unsigned short* lv = ldsV[cur];

    // S^T = K · Q^T : tile (kt, qt); D: col=q=lr, row=key=lq*4+reg
    f32x4 s[2][4] = {};
#pragma unroll
    for (int kt = 0; kt < 4; ++kt)
#pragma unroll
      for (int ks = 0; ks < 2; ++ks) {
        bf16x8 kf = *(const bf16x8*)(lk + (kt * 16 + lr) * 64 + (((ks * 4 + lq) ^ (lr & 7)) * 8));
        s[0][kt] = __builtin_amdgcn_mfma_f32_16x16x32_bf16(kf, qf[0][ks], s[0][kt], 0, 0, 0);
        s[1][kt] = __builtin_amdgcn_mfma_f32_16x16x32_bf16(kf, qf[1][ks], s[1][kt], 0, 0, 0);
      }

    // online softmax: per lane one q-row (q=lr), 16 keys in-lane
    float alr[2][4];
#pragma unroll
    for (int qt = 0; qt < 2; ++qt) {
      float mx = s[qt][0][0];
#pragma unroll
      for (int kt = 0; kt < 4; ++kt)
#pragma unroll
        for (int r = 0; r < 4; ++r) mx = fmaxf(mx, s[qt][kt][r]);
      mx = fmaxf(mx, __shfl_xor(mx, 16));
      mx = fmaxf(mx, __shfl_xor(mx, 32));
      float mnew = fmaxf(mrun[qt], mx);
      float al = exp2f(C * (mrun[qt] - mnew));
      mrun[qt] = mnew;
      float nmc = -C * mnew;
      float rs = 0.f;
#pragma unroll
      for (int kt = 0; kt < 4; ++kt)
#pragma unroll
        for (int r = 0; r < 4; ++r) {
          float p = exp2f(fmaf(s[qt][kt][r], C, nmc));
          s[qt][kt][r] = p; rs += p;
        }
      lpart[qt] = lpart[qt] * al + rs;   // partial (this lane's 16 keys); reduced at end
#pragma unroll
      for (int r = 0; r < 4; ++r) alr[qt][r] = __shfl(al, lq * 4 + r);
      // P store: 4 consecutive keys per reg -> one 8B write per (qt,kt)
#pragma unroll
      for (int kt = 0; kt < 4; ++kt) {
        uint2 pk;
        pk.x = pkbf(s[qt][kt][0], s[qt][kt][1]);
        pk.y = pkbf(s[qt][kt][2], s[qt][kt][3]);
        *(uint2*)(pw + (qt * 16 + lr) * 72 + kt * 16 + lq * 4) = pk;
      }
    }

    // rescale O accumulators
#pragma unroll
    for (int qt = 0; qt < 2; ++qt)
#pragma unroll
      for (int n = 0; n < 4; ++n) {
        oacc[qt][n][0] *= alr[qt][0]; oacc[qt][n][1] *= alr[qt][1];
        oacc[qt][n][2] *= alr[qt][2]; oacc[qt][n][3] *= alr[qt][3];
      }

    // O += P @ V  (A-frag: P rows q; B-frag: V^T rows d)
    bf16x8 pf[2][2];
#pragma unroll
    for (int qt = 0; qt < 2; ++qt)
#pragma unroll
      for (int ks = 0; ks < 2; ++ks)
        pf[qt][ks] = *(const bf16x8*)(pw + (qt * 16 + lr) * 72 + ks * 32 + lq * 8);
#pragma unroll
    for (int n = 0; n < 4; ++n)
#pragma unroll
      for (int ks = 0; ks < 2; ++ks) {
        bf16x8 vf = *(const bf16x8*)(lv + (n * 16 + lr) * 64 + (((ks * 4 + lq) ^ (lr & 7)) * 8));
        oacc[0][n] = __builtin_amdgcn_mfma_f32_16x16x32_bf16(pf[0][ks], vf, oacc[0][n], 0, 0, 0);
        oacc[1][n] = __builtin_amdgcn_mfma_f32_16x16x32_bf16(pf[1][ks], vf, oacc[1][n], 0, 0, 0);
      }

    __syncthreads();   // drains vmcnt (next tile staged) + protects buffer swap
    cur ^= 1;
  }

  // final normalize: full row-sum, redistribute to O-reg layout
  float invr[2][4];
#pragma unroll
  for (int qt = 0; qt < 2; ++qt) {
    float ls = lpart[qt];
    ls += __shfl_xor(ls, 16);
    ls += __shfl_xor(ls, 32);
    float iv = 1.f / ls;
#pragma unroll
    for (int r = 0; r < 4; ++r) invr[qt][r] = __shfl(iv, lq * 4 + r);
  }
#pragma unroll
  for (int qt = 0; qt < 2; ++qt)
#pragma unroll
    for (int n = 0; n < 4; ++n)
#pragma unroll
      for (int r = 0; r < 4; ++r) {
        int qi = q0 + qt * 16 + lq * 4 + r;
        O[((size_t)(b * SEQ + qi) * NHEADS + h) * HEADDIM + n * 16 + lr] =
            f2bf(oacc[qt][n][r] * invr[qt][r]);
      }
#undef STAGE_KV
}

// ---------------------------------------------------------------- launch
extern "C" void kernel_launch(void* const* d_in, const int* in_sizes, int n_in,
                              void* d_out, int out_size, void* d_ws, size_t ws_size,
                              hipStream_t stream) {
  const float* query = (const float*)d_in[0];
  const float* key_  = (const float*)d_in[1];
  const float* value = (const float*)d_in[2];
  const float* Wq = (const float*)d_in[3];
  const float* bq = (const float*)d_in[4];
  const float* Wk = (const float*)d_in[5];
  const float* bk = (const float*)d_in[6];
  const float* Wv = (const float*)d_in[7];
  const float* bv = (const float*)d_in[8];
  const float* Wo = (const float*)d_in[9];
  const float* bo = (const float*)d_in[10];

  const size_t NX = (size_t)M_ROWS * D_MODEL;       // 4M activations
  const size_t NW = (size_t)D_MODEL * D_MODEL;      // 1M weights

  char* ws = (char*)d_ws;
  size_t off = 0;
  auto alloc = [&](size_t bytes) { char* p = ws + off; off += (bytes + 255) & ~255ULL; return p; };
  unsigned short* Xq   = (unsigned short*)alloc(NX * 2);
  unsigned short* Xk   = (unsigned short*)alloc(NX * 2);
  unsigned short* Xv   = (unsigned short*)alloc(NX * 2);
  unsigned short* WqT  = (unsigned short*)alloc(NW * 2);
  unsigned short* WkT  = (unsigned short*)alloc(NW * 2);
  unsigned short* WvT  = (unsigned short*)alloc(NW * 2);
  unsigned short* WoT  = (unsigned short*)alloc(NW * 2);
  unsigned short* Qh   = (unsigned short*)alloc(NX * 2);
  unsigned short* Kh   = (unsigned short*)alloc(NX * 2);
  unsigned short* VTh  = (unsigned short*)alloc(NX * 2);
  unsigned short* Obuf = (unsigned short*)alloc(NX * 2);

  Cvt3Args ca;
  ca.x[0] = query; ca.x[1] = key_; ca.x[2] = value;
  ca.y[0] = Xq;    ca.y[1] = Xk;   ca.y[2] = Xv;
  cvt_bf16_3<<<dim3((unsigned)(NX / 4 / 256), 1, 3), 256, 0, stream>>>(ca, (int)NX);

  Wt4Args wa;
  wa.W[0] = Wq; wa.W[1] = Wk; wa.W[2] = Wv; wa.W[3] = Wo;
  wa.WT[0] = WqT; wa.WT[1] = WkT; wa.WT[2] = WvT; wa.WT[3] = WoT;
  wtrans4<<<dim3(32, 32, 4), dim3(32, 32), 0, stream>>>(wa);

  GemmArgs pa;
  pa.A[0] = Xq;  pa.A[1] = Xk;  pa.A[2] = Xv;
  pa.B[0] = WqT; pa.B[1] = WkT; pa.B[2] = WvT;
  pa.bias[0] = bq; pa.bias[1] = bk; pa.bias[2] = bv;
  pa.dst[0] = Qh; pa.dst[1] = Kh; pa.dst[2] = VTh;
  pa.mode0 = 0;
  gemm_bf16<<<dim3(D_MODEL / 128, M_ROWS / 128, 3), 256, 0, stream>>>(pa);

  flash_attn<<<dim3(SEQ / 128, BATCH * NHEADS), 256, 0, stream>>>(Qh, Kh, VTh, Obuf);

  GemmArgs fa = {};
  fa.A[0] = Obuf; fa.B[0] = WoT; fa.bias[0] = bo; fa.dst[0] = d_out; fa.mode0 = 3;
  gemm_bf16<<<dim3(D_MODEL / 128, M_ROWS / 128, 1), 256, 0, stream>>>(fa);
}

// Round 5
// 158.767 us; speedup vs baseline: 2.0429x; 1.1012x over previous
//
#include <hip/hip_runtime.h>
#include <hip/hip_bf16.h>
#include <stdint.h>

// Problem dims (fixed)
#define BATCH   2
#define SEQ     2048
#define D_MODEL 1024
#define NHEADS  16
#define HEADDIM 64
#define M_ROWS  (BATCH * SEQ)   // 4096

typedef __attribute__((ext_vector_type(8))) short bf16x8;   // 8 bf16 in 4 VGPRs
typedef __attribute__((ext_vector_type(4))) float f32x4;
typedef __attribute__((ext_vector_type(16))) float f32x16;
typedef __attribute__((ext_vector_type(2))) unsigned uint2v;

typedef __attribute__((address_space(3))) void       lds_void;
typedef const __attribute__((address_space(1))) void glb_void;

#define GLD_LDS16(g, l) \
  __builtin_amdgcn_global_load_lds((glb_void*)(g), (lds_void*)(l), 16, 0, 0)

__device__ __forceinline__ unsigned short f2bf(float f) {
  union { float f; unsigned u; } v; v.f = f;
  unsigned r = v.u + 0x7fff + ((v.u >> 16) & 1);   // round-to-nearest-even
  return (unsigned short)(r >> 16);
}

__device__ __forceinline__ unsigned pkbf(float a, float b) {
  __hip_bfloat162 h = __float22bfloat162_rn(float2{a, b});
  union { __hip_bfloat162 h; unsigned u; } cv; cv.h = h; return cv.u;  // a -> low 16
}

// swap upper 32 lanes of a with lower 32 lanes of b (both updated)
__device__ __forceinline__ void plane32_swap(unsigned& a, unsigned& b) {
#if __has_builtin(__builtin_amdgcn_permlane32_swap)
  uint2v r = __builtin_amdgcn_permlane32_swap(a, b, false, false);
  a = r[0]; b = r[1];
#else
  asm volatile("s_nop 1\n\tv_permlane32_swap_b32 %0, %1\n\ts_nop 1"
               : "+v"(a), "+v"(b));
#endif
}

// ---------------------------------------------------------------- converts
struct Cvt3Args { const float* x[3]; unsigned short* y[3]; };
__global__ void cvt_bf16_3(Cvt3Args a, int n) {
  const float* x = a.x[blockIdx.z];
  unsigned short* y = a.y[blockIdx.z];
  int i = (blockIdx.x * blockDim.x + threadIdx.x) * 4;
  if (i + 3 < n) {
    float4 v = *(const float4*)(x + i);
    ushort4 o; o.x = f2bf(v.x); o.y = f2bf(v.y); o.z = f2bf(v.z); o.w = f2bf(v.w);
    *(ushort4*)(y + i) = o;
  }
}

// W [K=1024][N=1024] fp32 -> WT [N][K] bf16  (4 weights batched on z)
struct Wt4Args { const float* W[4]; unsigned short* WT[4]; };
__global__ void wtrans4(Wt4Args a) {
  const float* W = a.W[blockIdx.z];
  unsigned short* WT = a.WT[blockIdx.z];
  __shared__ float t[32][33];
  int bx = blockIdx.x * 32, by = blockIdx.y * 32;
  int tx = threadIdx.x, ty = threadIdx.y;
  t[ty][tx] = W[(size_t)(by + ty) * D_MODEL + bx + tx];
  __syncthreads();
  WT[(size_t)(bx + ty) * D_MODEL + by + tx] = f2bf(t[tx][ty]);
}

// ---------------------------------------------------------------- GEMM
// C[M,N] = A[M,K] @ B[K,N] + bias, with B given transposed (BT[N][K]).
// 128x128 tile, BK=32, 4 waves (2x2), each wave 64x64 out (4x4 frags 16x16x32).
// mode 0/1: dst bf16 [B,H,L,HD]   (Q / K heads layout)
// mode 2  : dst bf16 [B,H,HD,L]   (V transposed)
// mode 3  : dst fp32 [M,N] row-major (final output)
struct GemmArgs {
  const unsigned short* A[3];
  const unsigned short* B[3];
  const float*          bias[3];
  void*                 dst[3];
  int                   mode0;
};

__global__ void gemm_bf16(GemmArgs ga) {
  const int z = blockIdx.z;
  const unsigned short* __restrict__ A  = ga.A[z];
  const unsigned short* __restrict__ BT = ga.B[z];
  const float* __restrict__ bias        = ga.bias[z];
  void* dst = ga.dst[z];
  const int mode = ga.mode0 + z;

  const int K = D_MODEL;
  const int bn0 = blockIdx.x * 128, bm0 = blockIdx.y * 128;
  __shared__ unsigned short lds_a[128 * 32];
  __shared__ unsigned short lds_b[128 * 32];
  const int tid = threadIdx.x, wave = tid >> 6, lane = tid & 63;
  const int wr = wave >> 1, wc = wave & 1;
  const int lr = lane & 15, lq = lane >> 4;
  const int srow = lane >> 2, scol = (lane & 3) * 8;   // staging: 16B per lane

  f32x4 acc[4][4] = {};

  for (int k0 = 0; k0 < K; k0 += 32) {
    __syncthreads();   // prev tile's ds_reads done before overwrite
#pragma unroll
    for (int c = 0; c < 2; ++c) {
      int ch  = c * 4 + wave;            // 8 chunks of 16 rows
      int row = ch * 16 + srow;
      GLD_LDS16(A  + (size_t)(bm0 + row) * K + k0 + scol, lds_a + ch * 512);
      GLD_LDS16(BT + (size_t)(bn0 + row) * K + k0 + scol, lds_b + ch * 512);
    }
    __syncthreads();   // drains vmcnt: LDS tiles ready

    bf16x8 af[4], bfr[4];
#pragma unroll
    for (int i = 0; i < 4; ++i) {
      af[i]  = *(const bf16x8*)(lds_a + (wr * 64 + i * 16 + lr) * 32 + lq * 8);
      bfr[i] = *(const bf16x8*)(lds_b + (wc * 64 + i * 16 + lr) * 32 + lq * 8);
    }
#pragma unroll
    for (int mi = 0; mi < 4; ++mi)
#pragma unroll
      for (int ni = 0; ni < 4; ++ni)
        acc[mi][ni] = __builtin_amdgcn_mfma_f32_16x16x32_bf16(af[mi], bfr[ni], acc[mi][ni], 0, 0, 0);
  }

  // epilogue: D mapping col = lane&15, row = (lane>>4)*4 + reg
#pragma unroll
  for (int mi = 0; mi < 4; ++mi) {
#pragma unroll
    for (int ni = 0; ni < 4; ++ni) {
      const int n  = bn0 + wc * 64 + ni * 16 + lr;
      const float bv = bias[n];
      const int mb = bm0 + wr * 64 + mi * 16 + lq * 4;
      f32x4 v = acc[mi][ni];
      if (mode == 3) {
        float* o = (float*)dst;
#pragma unroll
        for (int r = 0; r < 4; ++r) o[(size_t)(mb + r) * D_MODEL + n] = v[r] + bv;
      } else if (mode == 2) {
        // V^T: [B,H,HD,L]; 4 consecutive rows (l) pack to one 8B store
        const int b = mb >> 11, l = mb & 2047;
        const int h = n >> 6, hd = n & 63;
        ushort4 pk;
        pk.x = f2bf(v[0] + bv); pk.y = f2bf(v[1] + bv);
        pk.z = f2bf(v[2] + bv); pk.w = f2bf(v[3] + bv);
        *(ushort4*)((unsigned short*)dst + ((size_t)((b * NHEADS + h) * HEADDIM + hd)) * SEQ + l) = pk;
      } else {
        unsigned short* o = (unsigned short*)dst;
        const int h = n >> 6, hd = n & 63;
#pragma unroll
        for (int r = 0; r < 4; ++r) {
          int m = mb + r; int b = m >> 11, l = m & 2047;
          o[((size_t)(b * NHEADS + h) * SEQ + l) * HEADDIM + hd] = f2bf(v[r] + bv);
        }
      }
    }
  }
}

// ---------------------------------------------------------------- flash attention v3b
// 32x32x16 MFMA, in-register P via cvt_pk + permlane32_swap BUILTIN (T12), defer-rescale (T13).
// grid 512 (16 q-blocks x 32 heads), 4 waves/block, 32 q-rows/wave, 64-key LDS tiles dbuf.
// Swapped QK^T: S^T = mfma(K, Q): D col=q=lane&31, row=key=(reg&3)+8*(reg>>2)+4*(lane>>5).
__global__ __launch_bounds__(256, 2) void flash_attn(
    const unsigned short* __restrict__ Q,
    const unsigned short* __restrict__ Kb,
    const unsigned short* __restrict__ VT,
    unsigned short* __restrict__ O) {
  const int L = blockIdx.y * gridDim.x + blockIdx.x;   // linear dispatch id
  const int xcd = L & 7, slot = L >> 3;
  const int head = xcd * 4 + (slot >> 4);              // XCD k hosts heads 4k..4k+3
  const int qb   = slot & 15;
  const int b = head >> 4, h = head & 15;

  const int tid = threadIdx.x, wave = tid >> 6, lane = tid & 63;
  const int l31 = lane & 31, hi = lane >> 5;
  const int q0 = qb * 128 + wave * 32;

  const unsigned short* Qh = Q  + (size_t)head * SEQ * HEADDIM;
  const unsigned short* Kh = Kb + (size_t)head * SEQ * HEADDIM;
  const unsigned short* Vh = VT + (size_t)head * HEADDIM * SEQ;

  __shared__ unsigned short ldsK[2][64 * 64];
  __shared__ unsigned short ldsV[2][64 * 64];

  // staging: 8 x 16B chunks per 64-elem row; inverse-swizzled source (rule #21)
  const int r8 = lane >> 3;              // row&7 of the row this lane stages
  const int sc = (lane & 7) ^ r8;        // source chunk (involution)
#define STAGE_KV(buf, k0_)                                                          \
  {                                                                                 \
    _Pragma("unroll")                                                               \
    for (int it = 0; it < 2; ++it) {                                                \
      int row = it * 32 + wave * 8 + r8;                                            \
      GLD_LDS16(Kh + (size_t)(k0_ + row) * HEADDIM + sc * 8,                        \
                &ldsK[buf][(it * 256 + wave * 64) * 8]);                            \
      GLD_LDS16(Vh + (size_t)row * SEQ + (k0_) + sc * 8,                            \
                &ldsV[buf][(it * 256 + wave * 64) * 8]);                            \
    }                                                                               \
  }

  // Q fragments (B-operand: col q = l31, k = d = ds*16 + hi*8 + j)
  bf16x8 qf[4];
#pragma unroll
  for (int ds = 0; ds < 4; ++ds)
    qf[ds] = *(const bf16x8*)(Qh + (size_t)(q0 + l31) * HEADDIM + ds * 16 + hi * 8);

  f32x16 oacc[2] = {};
  float mrun = -1e30f, lpart = 0.f;
  const float C = 0.18033688011112f;     // 0.125 * log2(e)
  const float THR = 44.0f;               // ~8/C : defer-rescale threshold (P <= 2^8)

  STAGE_KV(0, 0);
  __syncthreads();
  int cur = 0;

  for (int t = 0; t < SEQ / 64; ++t) {
    if (t + 1 < SEQ / 64) STAGE_KV(cur ^ 1, (t + 1) * 64);

    const unsigned short* lk = ldsK[cur];
    const unsigned short* lv = ldsV[cur];

    // S^T = K · Q^T : 2 key-tiles of 32; A = K rows (key), B = Q cols (q)
    f32x16 s[2] = {};
#pragma unroll
    for (int kt = 0; kt < 2; ++kt) {
      const int row = kt * 32 + l31;
      const int swz = row & 7;
#pragma unroll
      for (int ds = 0; ds < 4; ++ds) {
        bf16x8 kf = *(const bf16x8*)(lk + row * 64 + (((ds * 2 + hi) ^ swz) * 8));
        s[kt] = __builtin_amdgcn_mfma_f32_32x32x16_bf16(kf, qf[ds], s[kt], 0, 0, 0);
      }
    }

    // row max: 32 in-lane (q = l31) + one cross-half shuffle
    float mx = fmaxf(s[0][0], s[0][1]);
#pragma unroll
    for (int kt = 0; kt < 2; ++kt)
#pragma unroll
      for (int r = (kt == 0 ? 2 : 0); r < 16; ++r) mx = fmaxf(mx, s[kt][r]);
    mx = fmaxf(mx, __shfl_xor(mx, 32));

    if (__any(mx > mrun + THR)) {        // rare rescale path (T13)
      float mnew = fmaxf(mrun, mx);
      float al = exp2f(C * (mrun - mnew));
      mrun = mnew;
      lpart *= al;
#pragma unroll
      for (int reg = 0; reg < 16; ++reg) {
        int qrow = (reg & 3) + 8 * (reg >> 2) + 4 * hi;
        float alr = __shfl(al, qrow);
        oacc[0][reg] *= alr; oacc[1][reg] *= alr;
      }
    }

    // P = exp2(C*s - C*m), pack pairs of consecutive keys to bf16x2
    const float nmc = -C * mrun;
    float rs = 0.f;
    unsigned u[2][8];
#pragma unroll
    for (int kt = 0; kt < 2; ++kt)
#pragma unroll
      for (int m = 0; m < 8; ++m) {
        float p0 = exp2f(fmaf(s[kt][2 * m],     C, nmc));
        float p1 = exp2f(fmaf(s[kt][2 * m + 1], C, nmc));
        rs += p0 + p1;
        u[kt][m] = pkbf(p0, p1);
      }
    lpart += rs;

    // O += P @ V : pf via permlane32_swap (keys lane-local -> A-frag rows q)
#pragma unroll
    for (int ks = 0; ks < 4; ++ks) {
      const int kt = ks >> 1, a = 4 * (ks & 1);
      unsigned c0 = u[kt][a],     c2 = u[kt][a + 2];
      unsigned c1 = u[kt][a + 1], c3 = u[kt][a + 3];
      plane32_swap(c0, c2);
      plane32_swap(c1, c3);
      union { unsigned w[4]; bf16x8 v; } pf;
      pf.w[0] = c0; pf.w[1] = c1; pf.w[2] = c2; pf.w[3] = c3;
#pragma unroll
      for (int dt = 0; dt < 2; ++dt) {
        const int row = dt * 32 + l31;
        bf16x8 vf = *(const bf16x8*)(lv + row * 64 + (((ks * 2 + hi) ^ (row & 7)) * 8));
        oacc[dt] = __builtin_amdgcn_mfma_f32_32x32x16_bf16(pf.v, vf, oacc[dt], 0, 0, 0);
      }
    }

    __syncthreads();   // drains vmcnt (next tile staged) + protects buffer swap
    cur ^= 1;
  }

  // final normalize: combine the two key-halves, broadcast inv to O-row layout
  lpart += __shfl_xor(lpart, 32);
  float iv = 1.f / lpart;
#pragma unroll
  for (int reg = 0; reg < 16; ++reg) {
    int qrow = (reg & 3) + 8 * (reg >> 2) + 4 * hi;
    float ivr = __shfl(iv, qrow);
    int qi = q0 + qrow;
#pragma unroll
    for (int dt = 0; dt < 2; ++dt)
      O[((size_t)(b * SEQ + qi) * NHEADS + h) * HEADDIM + dt * 32 + l31] =
          f2bf(oacc[dt][reg] * ivr);
  }
#undef STAGE_KV
}

// ---------------------------------------------------------------- launch
extern "C" void kernel_launch(void* const* d_in, const int* in_sizes, int n_in,
                              void* d_out, int out_size, void* d_ws, size_t ws_size,
                              hipStream_t stream) {
  const float* query = (const float*)d_in[0];
  const float* key_  = (const float*)d_in[1];
  const float* value = (const float*)d_in[2];
  const float* Wq = (const float*)d_in[3];
  const float* bq = (const float*)d_in[4];
  const float* Wk = (const float*)d_in[5];
  const float* bk = (const float*)d_in[6];
  const float* Wv = (const float*)d_in[7];
  const float* bv = (const float*)d_in[8];
  const float* Wo = (const float*)d_in[9];
  const float* bo = (const float*)d_in[10];

  const size_t NX = (size_t)M_ROWS * D_MODEL;       // 4M activations
  const size_t NW = (size_t)D_MODEL * D_MODEL;      // 1M weights

  char* ws = (char*)d_ws;
  size_t off = 0;
  auto alloc = [&](size_t bytes) { char* p = ws + off; off += (bytes + 255) & ~255ULL; return p; };
  unsigned short* Xq   = (unsigned short*)alloc(NX * 2);
  unsigned short* Xk   = (unsigned short*)alloc(NX * 2);
  unsigned short* Xv   = (unsigned short*)alloc(NX * 2);
  unsigned short* WqT  = (unsigned short*)alloc(NW * 2);
  unsigned short* WkT  = (unsigned short*)alloc(NW * 2);
  unsigned short* WvT  = (unsigned short*)alloc(NW * 2);
  unsigned short* WoT  = (unsigned short*)alloc(NW * 2);
  unsigned short* Qh   = (unsigned short*)alloc(NX * 2);
  unsigned short* Kh   = (unsigned short*)alloc(NX * 2);
  unsigned short* VTh  = (unsigned short*)alloc(NX * 2);
  unsigned short* Obuf = (unsigned short*)alloc(NX * 2);

  Cvt3Args ca;
  ca.x[0] = query; ca.x[1] = key_; ca.x[2] = value;
  ca.y[0] = Xq;    ca.y[1] = Xk;   ca.y[2] = Xv;
  cvt_bf16_3<<<dim3((unsigned)(NX / 4 / 256), 1, 3), 256, 0, stream>>>(ca, (int)NX);

  Wt4Args wa;
  wa.W[0] = Wq; wa.W[1] = Wk; wa.W[2] = Wv; wa.W[3] = Wo;
  wa.WT[0] = WqT; wa.WT[1] = WkT; wa.WT[2] = WvT; wa.WT[3] = WoT;
  wtrans4<<<dim3(32, 32, 4), dim3(32, 32), 0, stream>>>(wa);

  GemmArgs pa;
  pa.A[0] = Xq;  pa.A[1] = Xk;  pa.A[2] = Xv;
  pa.B[0] = WqT; pa.B[1] = WkT; pa.B[2] = WvT;
  pa.bias[0] = bq; pa.bias[1] = bk; pa.bias[2] = bv;
  pa.dst[0] = Qh; pa.dst[1] = Kh; pa.dst[2] = VTh;
  pa.mode0 = 0;
  gemm_bf16<<<dim3(D_MODEL / 128, M_ROWS / 128, 3), 256, 0, stream>>>(pa);

  flash_attn<<<dim3(SEQ / 128, BATCH * NHEADS), 256, 0, stream>>>(Qh, Kh, VTh, Obuf);

  GemmArgs fa = {};
  fa.A[0] = Obuf; fa.B[0] = WoT; fa.bias[0] = bo; fa.dst[0] = d_out; fa.mode0 = 3;
  gemm_bf16<<<dim3(D_MODEL / 128, M_ROWS / 128, 1), 256, 0, stream>>>(fa);
}